// Round 21
// baseline (1673.443 us; speedup 1.0000x reference)
//
#include <hip/hip_runtime.h>

#define TT 2048

typedef float v2f __attribute__((ext_vector_type(2)));
typedef _Float16 h2v __attribute__((ext_vector_type(2)));

__device__ __forceinline__ v2f mk2(float a, float b) { v2f r; r.x = a; r.y = b; return r; }
__device__ __forceinline__ float rcpf(float x) { return __builtin_amdgcn_rcpf(x); }
__device__ __forceinline__ float fsig(float x) { return rcpf(1.0f + __expf(-x)); }
__device__ __forceinline__ float ftanh(float x) {
    return fmaf(2.0f, rcpf(1.0f + __expf(-2.0f * x)), -1.0f);
}

template<int C>
__device__ __forceinline__ float dppmov(float s) {
    return __int_as_float(__builtin_amdgcn_update_dpp(
        __float_as_int(s), __float_as_int(s), C, 0xF, 0xF, false));
}
template<int Q>
__device__ __forceinline__ float qbcast(float x) {
    return __int_as_float(__builtin_amdgcn_update_dpp(
        __float_as_int(x), __float_as_int(x), Q * 0x55, 0xF, 0xF, false));
}

#if __has_builtin(__builtin_amdgcn_fdot2)
#define DOT2(a, b, c) __builtin_amdgcn_fdot2((a), (b), (c), false)
#else
#define DOT2(a, b, c) fmaf((float)(a).x, (float)(b).x, \
                      fmaf((float)(a).y, (float)(b).y, (c)))
#endif

__device__ __forceinline__ h2v pk2(float a, float b) {
#if __has_builtin(__builtin_amdgcn_cvt_pkrtz)
    return __builtin_bit_cast(h2v, __builtin_amdgcn_cvt_pkrtz(a, b));
#else
    h2v r; r.x = (_Float16)a; r.y = (_Float16)b; return r;
#endif
}
__device__ __forceinline__ h2v bch(int v) { return __builtin_bit_cast(h2v, v); }

// ===== Kernel 1: TWO ELEMENTS PER WAVE, register-budget-fixed (R20 redo) ====
// 256 blocks x 64 threads. R20 post-mortem: live set ~290 VGPR > 256 arch cap
// -> spill (VGPR_Count 132, VALUBusy 36->20%). Per-elem step cost STILL
// improved (879 vs R19's 1021 cyc) — the interleave works; the budget broke.
// Fix: W2 (32 h2v regs) -> static LDS (576 B, [4][72] f16 rows on distinct
// banks), read back as conflict-free b128 only in the per-16-step batch
// phase, where the step-phase registers are dead. New peak live ~230 < 256.
// Everything else = R20: shared 128-h2v W1, 8 independent dot2 chains
// (4 gates x 2 elems), two f16 LDS rings, zero barriers, zero cross-wave.
__global__ __launch_bounds__(64)
__attribute__((amdgpu_waves_per_eu(1, 1)))
void lstm1_f16x2(const float* __restrict__ x,
                 const float* __restrict__ W1,
                 const float* __restrict__ b1,
                 const float* __restrict__ W2,
                 float* __restrict__ zout)
{
    __shared__ __align__(16) float xA[TT], xB[TT];
    __shared__ __align__(16) _Float16 ringA[16 * 72], ringB[16 * 72];
    __shared__ __align__(16) _Float16 w2lds[4][72];   // rows on distinct banks

    const int lane = threadIdx.x & 63;
    const int e    = blockIdx.x;          // element pair id
    const int u    = lane;

    for (int i = lane; i < TT; i += 64) {
        xA[i] = x[(size_t)(2 * e) * TT + i];
        xB[i] = x[(size_t)(2 * e + 1) * TT + i];
    }
    for (int i = lane; i < 576; i += 64) {
        ((int*)ringA)[i] = 0; ((int*)ringB)[i] = 0;
    }
    // W2 h-part into LDS (f16): row g, col k = W2[k*4+g]
    w2lds[0][lane] = (_Float16)W2[lane * 4 + 0];
    w2lds[1][lane] = (_Float16)W2[lane * 4 + 1];
    w2lds[2][lane] = (_Float16)W2[lane * 4 + 2];
    w2lds[3][lane] = (_Float16)W2[lane * 4 + 3];

    // Layer-1 weights (shared by both elems): gate G col = G*64+u, 32 h2v/gate.
#define DWQ(G, GO, q) \
    const h2v w##G##q##x = pk2(W1[(1+8*(q))*256 + (GO)*64 + u], W1[(2+8*(q))*256 + (GO)*64 + u]); \
    const h2v w##G##q##y = pk2(W1[(3+8*(q))*256 + (GO)*64 + u], W1[(4+8*(q))*256 + (GO)*64 + u]); \
    const h2v w##G##q##z = pk2(W1[(5+8*(q))*256 + (GO)*64 + u], W1[(6+8*(q))*256 + (GO)*64 + u]); \
    const h2v w##G##q##w = pk2(W1[(7+8*(q))*256 + (GO)*64 + u], W1[(8+8*(q))*256 + (GO)*64 + u]);
    DWQ(I, 0, 0) DWQ(I, 0, 1) DWQ(I, 0, 2) DWQ(I, 0, 3)
    DWQ(I, 0, 4) DWQ(I, 0, 5) DWQ(I, 0, 6) DWQ(I, 0, 7)
    DWQ(J, 1, 0) DWQ(J, 1, 1) DWQ(J, 1, 2) DWQ(J, 1, 3)
    DWQ(J, 1, 4) DWQ(J, 1, 5) DWQ(J, 1, 6) DWQ(J, 1, 7)
    DWQ(F, 2, 0) DWQ(F, 2, 1) DWQ(F, 2, 2) DWQ(F, 2, 3)
    DWQ(F, 2, 4) DWQ(F, 2, 5) DWQ(F, 2, 6) DWQ(F, 2, 7)
    DWQ(O, 3, 0) DWQ(O, 3, 1) DWQ(O, 3, 2) DWQ(O, 3, 3)
    DWQ(O, 3, 4) DWQ(O, 3, 5) DWQ(O, 3, 6) DWQ(O, 3, 7)
#undef DWQ

    const float w0I = W1[u],        bI = b1[u];
    const float w0J = W1[64 + u],   bJ = b1[64 + u];
    const float w0F = W1[128 + u],  bF = b1[128 + u] + 1.0f;  // forget bias
    const float w0O = W1[192 + u],  bO = b1[192 + u];

    const int tl = lane >> 2, gq = lane & 3;   // layer-2 batch role

    float c1A = 0.0f, c1B = 0.0f;
    __syncthreads();   // single wave: covers init stores

    float* __restrict__ zbA = zout + (size_t)(2 * e) * TT * 4;
    float* __restrict__ zbB = zout + (size_t)(2 * e + 1) * TT * 4;

#define DOTQ(E, q, v) \
    accI##E = DOT2(bch((v).x), wI##q##x, accI##E); \
    accI##E = DOT2(bch((v).y), wI##q##y, accI##E); \
    accI##E = DOT2(bch((v).z), wI##q##z, accI##E); \
    accI##E = DOT2(bch((v).w), wI##q##w, accI##E); \
    accJ##E = DOT2(bch((v).x), wJ##q##x, accJ##E); \
    accJ##E = DOT2(bch((v).y), wJ##q##y, accJ##E); \
    accJ##E = DOT2(bch((v).z), wJ##q##z, accJ##E); \
    accJ##E = DOT2(bch((v).w), wJ##q##w, accJ##E); \
    accF##E = DOT2(bch((v).x), wF##q##x, accF##E); \
    accF##E = DOT2(bch((v).y), wF##q##y, accF##E); \
    accF##E = DOT2(bch((v).z), wF##q##z, accF##E); \
    accF##E = DOT2(bch((v).w), wF##q##w, accF##E); \
    accO##E = DOT2(bch((v).x), wO##q##x, accO##E); \
    accO##E = DOT2(bch((v).y), wO##q##y, accO##E); \
    accO##E = DOT2(bch((v).z), wO##q##z, accO##E); \
    accO##E = DOT2(bch((v).w), wO##q##w, accO##E);

    for (int t = 0; t < TT; ++t) {
        const int rs = ((t - 1) & 15) * 72;
        const int4* hpA = (const int4*)&ringA[rs];
        const int4* hpB = (const int4*)&ringB[rs];
        const int4 a0 = hpA[0], a1 = hpA[1], a2 = hpA[2], a3 = hpA[3];
        const int4 b0 = hpB[0], b1q = hpB[1], b2q = hpB[2], b3q = hpB[3];
        const int4 a4 = hpA[4], a5 = hpA[5], a6 = hpA[6], a7 = hpA[7];
        const int4 b4 = hpB[4], b5 = hpB[5], b6 = hpB[6], b7 = hpB[7];
        const float xtA = xA[t], xtB = xB[t];
        float accIA = fmaf(xtA, w0I, bI), accIB = fmaf(xtB, w0I, bI);
        float accJA = fmaf(xtA, w0J, bJ), accJB = fmaf(xtB, w0J, bJ);
        float accFA = fmaf(xtA, w0F, bF), accFB = fmaf(xtB, w0F, bF);
        float accOA = fmaf(xtA, w0O, bO), accOB = fmaf(xtB, w0O, bO);
        // interleave A/B quads: 8 independent accumulation chains
        DOTQ(A, 0, a0) DOTQ(B, 0, b0)
        DOTQ(A, 1, a1) DOTQ(B, 1, b1q)
        DOTQ(A, 2, a2) DOTQ(B, 2, b2q)
        DOTQ(A, 3, a3) DOTQ(B, 3, b3q)
        DOTQ(A, 4, a4) DOTQ(B, 4, b4)
        DOTQ(A, 5, a5) DOTQ(B, 5, b5)
        DOTQ(A, 6, a6) DOTQ(B, 6, b6)
        DOTQ(A, 7, a7) DOTQ(B, 7, b7)
        // nonlinearities (f32), two independent chains
        const float iA = fsig(accIA),  iB = fsig(accIB);
        const float jA = ftanh(accJA), jB = ftanh(accJB);
        const float fA = fsig(accFA),  fB = fsig(accFB);
        const float oA = fsig(accOA),  oB = fsig(accOB);
        c1A = fmaf(c1A, fA, iA * jA);
        c1B = fmaf(c1B, fB, iB * jB);
        const float h1A = ftanh(c1A) * oA;
        const float h1B = ftanh(c1B) * oB;
        const int ws = (t & 15) * 72 + u;
        ringA[ws] = (_Float16)h1A;    // same-wave visible via lgkm
        ringB[ws] = (_Float16)h1B;

        // layer-2 partial batch every 16 steps, both elems (W2 from LDS —
        // step registers are dead here, so batch temporaries reuse them)
        if ((t & 15) == 15) {
            const int4* hbA = (const int4*)&ringA[tl * 72];
            const int4* hbB = (const int4*)&ringB[tl * 72];
            const int4* w2q = (const int4*)&w2lds[gq][0];
            float zA = 0.0f, zB = 0.0f;
#pragma unroll
            for (int q = 0; q < 8; ++q) {
                const int4 wv = w2q[q];
                const int4 va = hbA[q];
                const int4 vb = hbB[q];
                zA = DOT2(bch(va.x), bch(wv.x), zA);
                zB = DOT2(bch(vb.x), bch(wv.x), zB);
                zA = DOT2(bch(va.y), bch(wv.y), zA);
                zB = DOT2(bch(vb.y), bch(wv.y), zB);
                zA = DOT2(bch(va.z), bch(wv.z), zA);
                zB = DOT2(bch(vb.z), bch(wv.z), zB);
                zA = DOT2(bch(va.w), bch(wv.w), zA);
                zB = DOT2(bch(vb.w), bch(wv.w), zB);
            }
            const size_t zoff = (size_t)(t - 15 + tl) * 4 + gq;
            zbA[zoff] = zA;
            zbB[zoff] = zB;
        }
    }
#undef DOTQ
}

// ===== Kernel 2: layer-2 recurrence (R13, proven, format unchanged) =====
__global__ __launch_bounds__(64)
void lstm2_chain(const float* __restrict__ zp,
                 const float* __restrict__ W2,
                 const float* __restrict__ b2,
                 float* __restrict__ out)
{
    const int lane = threadIdx.x & 63;
    const int e    = lane >> 2;
    const int g    = lane & 3;
    const int elem = (blockIdx.x << 4) + e;

    const float w2h = W2[256 + g];
    const float bb  = b2[g] + ((g == 2) ? 1.0f : 0.0f);
    const float nlm = (g == 1) ? -2.0f : -1.0f;
    const float k2  = (g == 1) ?  2.0f :  1.0f;
    const float k3  = (g == 1) ? -1.0f :  0.0f;

    const float* __restrict__ zrow = zp + (size_t)elem * TT * 4 + g;
    float* __restrict__ orow = out + (size_t)elem * TT;

    float c2 = 0.0f, h2 = 0.0f;

    float zc[16];
#pragma unroll
    for (int k = 0; k < 16; ++k) zc[k] = zrow[k << 2];

    for (int t0 = 0; t0 < TT; t0 += 16) {
        float zn[16];
        if (t0 + 16 < TT) {
#pragma unroll
            for (int k = 0; k < 16; ++k) zn[k] = zrow[((t0 + 16 + k) << 2)];
        }
        float st0 = 0.f, st1 = 0.f, st2 = 0.f, st3 = 0.f;
#pragma unroll
        for (int k = 0; k < 16; ++k) {
            const float arg = fmaf(w2h, h2, zc[k] + bb);
            const float ev  = __expf(arg * nlm);
            const float rv  = rcpf(1.0f + ev);
            const float v   = fmaf(k2, rv, k3);
            const float vi = qbcast<0>(v), vj = qbcast<1>(v);
            const float vf = qbcast<2>(v), vo = qbcast<3>(v);
            c2 = fmaf(c2, vf, vi * vj);
            h2 = ftanh(c2) * vo;
            const bool mine = (g == (k & 3));
            if ((k >> 2) == 0) st0 = mine ? h2 : st0;
            else if ((k >> 2) == 1) st1 = mine ? h2 : st1;
            else if ((k >> 2) == 2) st2 = mine ? h2 : st2;
            else st3 = mine ? h2 : st3;
        }
        orow[t0 + g]      = st0;
        orow[t0 + 4 + g]  = st1;
        orow[t0 + 8 + g]  = st2;
        orow[t0 + 12 + g] = st3;
#pragma unroll
        for (int k = 0; k < 16; ++k) zc[k] = zn[k];
    }
}

// ===== Fallback: monolithic (R11 core, proven) =====
__global__ __launch_bounds__(512)
__attribute__((amdgpu_waves_per_eu(4, 4)))
void lstm2_mono(const float* __restrict__ x,
                const float* __restrict__ W1,
                const float* __restrict__ b1,
                const float* __restrict__ W2,
                const float* __restrict__ b2,
                float* __restrict__ out)
{
    __shared__ __align__(16) float xall[TT + 4];
    __shared__ __align__(16) float h1x[2][80];
    __shared__ __align__(16) float zpq[4][4];
    __shared__ __align__(16) float h2buf[2][64];

    const int tid  = threadIdx.x;
    const int wave = tid >> 6;
    const int lane = tid & 63;
    const int b    = blockIdx.x;

    for (int i = tid; i < TT; i += 512) xall[i] = x[b * TT + i];
    if (tid < 4) xall[TT + tid] = 0.0f;

    const int u    = lane >> 3;
    const int h    = (lane >> 2) & 1;
    const int g    = lane & 3;
    const int unit = (wave << 3) + u;
    const int col  = (g << 6) + unit;

#define DECLW(k) const v2f wq##k = mk2(W1[(1 + 32*h + 2*(k)) * 256 + col], \
                                       W1[(2 + 32*h + 2*(k)) * 256 + col]);
    DECLW(0)  DECLW(1)  DECLW(2)  DECLW(3)
    DECLW(4)  DECLW(5)  DECLW(6)  DECLW(7)
    DECLW(8)  DECLW(9)  DECLW(10) DECLW(11)
    DECLW(12) DECLW(13) DECLW(14) DECLW(15)
#undef DECLW

    const float w0x   = (h == 0) ? W1[col] : 0.0f;
    const float biasF = (h == 0) ? (b1[col] + ((g == 2) ? 1.0f : 0.0f)) : 0.0f;
    const float nlm   = (g == 1) ? -2.0f : -1.0f;
    const bool  isj   = (g == 1);

    const float w2g  = W2[lane * 4 + (wave & 3)];
    const float w2h0 = W2[256], w2h1 = W2[257], w2h2 = W2[258], w2h3 = W2[259];
    const float b20 = b2[0], b21 = b2[1], b22 = b2[2], b23 = b2[3];

    float c1 = 0.0f;
    float c2 = 0.0f, h2v2 = 0.0f;

    const int hbase = h * 48;
    const int ridx  = lane + ((lane >> 5) << 4);
    const int widx  = (unit < 32) ? unit : unit + 16;

    if (tid < 160) ((float*)h1x)[tid] = 0.0f;
    __syncthreads();

    float* __restrict__ outb = out + b * TT;

#define WSUM(s) ({ float _s = (s);                                            \
    _s += dppmov<0x111>(_s); _s += dppmov<0x112>(_s); _s += dppmov<0x114>(_s);\
    _s += dppmov<0x118>(_s); _s += dppmov<0x142>(_s); _s += dppmov<0x143>(_s);\
    _s; })

#define STEP(P, t, xv)                                                        \
    {                                                                         \
        if ((t) < TT) {                                                       \
            const float4* hp = (const float4*)&h1x[P][hbase];                 \
            const float4 q0 = hp[0], q1 = hp[1], q2 = hp[2], q3 = hp[3];      \
            const float4 q4 = hp[4], q5 = hp[5], q6 = hp[6], q7 = hp[7];      \
            v2f a0 = mk2(fmaf((xv), w0x, biasF), 0.0f);                       \
            v2f a1 = mk2(0.f, 0.f), a2 = mk2(0.f, 0.f), a3 = mk2(0.f, 0.f);  \
            a0 = __builtin_elementwise_fma(mk2(q0.x, q0.y), wq0,  a0);        \
            a1 = __builtin_elementwise_fma(mk2(q0.z, q0.w), wq1,  a1);        \
            a2 = __builtin_elementwise_fma(mk2(q1.x, q1.y), wq2,  a2);        \
            a3 = __builtin_elementwise_fma(mk2(q1.z, q1.w), wq3,  a3);        \
            a0 = __builtin_elementwise_fma(mk2(q2.x, q2.y), wq4,  a0);        \
            a1 = __builtin_elementwise_fma(mk2(q2.z, q2.w), wq5,  a1);        \
            a2 = __builtin_elementwise_fma(mk2(q3.x, q3.y), wq6,  a2);        \
            a3 = __builtin_elementwise_fma(mk2(q3.z, q3.w), wq7,  a3);        \
            a0 = __builtin_elementwise_fma(mk2(q4.x, q4.y), wq8,  a0);        \
            a1 = __builtin_elementwise_fma(mk2(q4.z, q4.w), wq9,  a1);        \
            a2 = __builtin_elementwise_fma(mk2(q5.x, q5.y), wq10, a2);        \
            a3 = __builtin_elementwise_fma(mk2(q5.z, q5.w), wq11, a3);        \
            a0 = __builtin_elementwise_fma(mk2(q6.x, q6.y), wq12, a0);        \
            a1 = __builtin_elementwise_fma(mk2(q6.z, q6.w), wq13, a1);        \
            a2 = __builtin_elementwise_fma(mk2(q7.x, q7.y), wq14, a2);        \
            a3 = __builtin_elementwise_fma(mk2(q7.z, q7.w), wq15, a3);        \
            const v2f sv = (a0 + a1) + (a2 + a3);                             \
            const float zh = sv.x + sv.y;                                     \
            const float tshr = dppmov<0x114>(zh);                             \
            const float tshl = dppmov<0x104>(zh);                             \
            const float zfull = zh + (h ? tshr : tshl);                       \
            const float e = __expf(zfull * nlm);                              \
            const float r = rcpf(1.0f + e);                                   \
            const float v = isj ? fmaf(2.0f, r, -1.0f) : r;                   \
            const float gi = qbcast<0>(v), gj = qbcast<1>(v);                 \
            const float gf = qbcast<2>(v), go = qbcast<3>(v);                 \
            c1 = fmaf(c1, gf, gi * gj);                                       \
            const float h1v = ftanh(c1) * go;                                 \
            if ((lane & 7) == 0) h1x[(P) ^ 1][widx] = h1v;                    \
        }                                                                     \
        if (wave < 4 && (t) >= 1 && (t) <= TT) {                              \
            const float s = WSUM(h1x[P][ridx] * w2g);                         \
            if (lane == 63) zpq[((t) - 1) & 3][wave] = s;                     \
        }                                                                     \
        if (wave == 7 && lane == 0 && (t) >= 2 && (t) <= TT + 1) {            \
            const int st = (t) - 2;                                           \
            const float4 z4 = *(const float4*)zpq[st & 3];                    \
            const float zi = z4.x + fmaf(h2v2, w2h0, b20);                    \
            const float zj = z4.y + fmaf(h2v2, w2h1, b21);                    \
            const float zf = z4.z + fmaf(h2v2, w2h2, b22);                    \
            const float zo = z4.w + fmaf(h2v2, w2h3, b23);                    \
            c2 = c2 * fsig(zf + 1.0f) + fsig(zi) * ftanh(zj);                 \
            h2v2 = ftanh(c2) * fsig(zo);                                      \
            h2buf[(st >> 6) & 1][st & 63] = h2v2;                             \
        }                                                                     \
        __syncthreads();                                                      \
        if (wave == 4 && (t) >= 66 && ((t) & 63) == 2) {                      \
            const int blk = ((t) - 66) >> 6;                                  \
            outb[(blk << 6) + lane] = h2buf[blk & 1][lane];                   \
        }                                                                     \
    }

    for (int it = 0; it <= TT + 2; it += 2) {
        const float2 x2 = *(const float2*)&xall[it];
        STEP(0, it,     x2.x)
        STEP(1, it + 1, x2.y)
    }
#undef STEP
#undef WSUM
}

extern "C" void kernel_launch(void* const* d_in, const int* in_sizes, int n_in,
                              void* d_out, int out_size, void* d_ws, size_t ws_size,
                              hipStream_t stream)
{
    const float* x  = (const float*)d_in[0];
    const float* W1 = (const float*)d_in[1];
    const float* b1 = (const float*)d_in[2];
    const float* W2 = (const float*)d_in[3];
    const float* b2 = (const float*)d_in[4];
    float* out = (float*)d_out;

    const size_t need = (size_t)512 * TT * 4 * sizeof(float);   // 16.8 MB
    if (ws_size >= need) {
        float* zp = (float*)d_ws;
        lstm1_f16x2<<<256, 64, 0, stream>>>(x, W1, b1, W2, zp);
        lstm2_chain<<<512 / 16, 64, 0, stream>>>(zp, W2, b2, out);
    } else {
        lstm2_mono<<<512, 512, 0, stream>>>(x, W1, b1, W2, b2, out);
    }
}

// Round 22
// 1039.380 us; speedup vs baseline: 1.6100x; 1.6100x over previous
//
#include <hip/hip_runtime.h>

#define TT 2048

typedef float v2f __attribute__((ext_vector_type(2)));
typedef _Float16 h2v __attribute__((ext_vector_type(2)));

__device__ __forceinline__ v2f mk2(float a, float b) { v2f r; r.x = a; r.y = b; return r; }
__device__ __forceinline__ float rcpf(float x) { return __builtin_amdgcn_rcpf(x); }
__device__ __forceinline__ float fsig(float x) { return rcpf(1.0f + __expf(-x)); }
__device__ __forceinline__ float ftanh(float x) {
    return fmaf(2.0f, rcpf(1.0f + __expf(-2.0f * x)), -1.0f);
}

template<int C>
__device__ __forceinline__ float dppmov(float s) {
    return __int_as_float(__builtin_amdgcn_update_dpp(
        __float_as_int(s), __float_as_int(s), C, 0xF, 0xF, false));
}
template<int Q>
__device__ __forceinline__ float qbcast(float x) {
    return __int_as_float(__builtin_amdgcn_update_dpp(
        __float_as_int(x), __float_as_int(x), Q * 0x55, 0xF, 0xF, false));
}

#if __has_builtin(__builtin_amdgcn_fdot2)
#define DOT2(a, b, c) __builtin_amdgcn_fdot2((a), (b), (c), false)
#else
#define DOT2(a, b, c) fmaf((float)(a).x, (float)(b).x, \
                      fmaf((float)(a).y, (float)(b).y, (c)))
#endif

__device__ __forceinline__ h2v pk2(float a, float b) {
#if __has_builtin(__builtin_amdgcn_cvt_pkrtz)
    return __builtin_bit_cast(h2v, __builtin_amdgcn_cvt_pkrtz(a, b));
#else
    h2v r; r.x = (_Float16)a; r.y = (_Float16)b; return r;
#endif
}
__device__ __forceinline__ h2v bch(int v) { return __builtin_bit_cast(h2v, v); }

#if __has_attribute(amdgpu_num_vgpr)
#define FORCE_VGPR __attribute__((amdgpu_num_vgpr(256)))
#else
#define FORCE_VGPR
#endif

// ===== Kernel 1: ONE WAVE PER ELEMENT (R19 base = proven 871us) + fixes ====
// R20/R21 post-mortem: the backend ignores amdgpu_waves_per_eu for its
// remat/pressure target — VGPR pinned ~124-132 across wpe(1,1)/(2,2), so
// even R19 reloads part of W1/W2 from L2 every step (124 < 160 needed),
// naked latency at 0.5 waves/SIMD. Fixes this round:
// (1) amdgpu_num_vgpr(256): directly sets the RA budget (documented clang
//     attr), bypassing the ignored wpe-derived target -> weights resident.
// (2) dot2 chains split 32 -> 2x16 (8 accumulators): halves arith dep depth.
// (3) x-part folded at the END (z = fmaf(x,w0,acc0+acc1)): x LDS-read off
//     the chain front. Everything else identical to R19.
__global__ __launch_bounds__(64)
__attribute__((amdgpu_waves_per_eu(2, 2)))
FORCE_VGPR
void lstm1_f16(const float* __restrict__ x,
               const float* __restrict__ W1,
               const float* __restrict__ b1,
               const float* __restrict__ W2,
               float* __restrict__ zout)
{
    __shared__ __align__(16) float xall[TT];
    __shared__ __align__(16) _Float16 hring[16 * 72];  // 144B/slot

    const int lane = threadIdx.x & 63;
    const int e    = blockIdx.x;
    const int u    = lane;

    for (int i = lane; i < TT; i += 64) xall[i] = x[(size_t)e * TT + i];
    for (int i = lane; i < 576; i += 64) ((int*)hring)[i] = 0;

    // Layer-1 weights: gate G column = G*64+u; h rows 1..64 as 32 half2/gate.
#define DWQ(G, GO, q) \
    const h2v w##G##q##x = pk2(W1[(1+8*(q))*256 + (GO)*64 + u], W1[(2+8*(q))*256 + (GO)*64 + u]); \
    const h2v w##G##q##y = pk2(W1[(3+8*(q))*256 + (GO)*64 + u], W1[(4+8*(q))*256 + (GO)*64 + u]); \
    const h2v w##G##q##z = pk2(W1[(5+8*(q))*256 + (GO)*64 + u], W1[(6+8*(q))*256 + (GO)*64 + u]); \
    const h2v w##G##q##w = pk2(W1[(7+8*(q))*256 + (GO)*64 + u], W1[(8+8*(q))*256 + (GO)*64 + u]);
    DWQ(I, 0, 0) DWQ(I, 0, 1) DWQ(I, 0, 2) DWQ(I, 0, 3)
    DWQ(I, 0, 4) DWQ(I, 0, 5) DWQ(I, 0, 6) DWQ(I, 0, 7)
    DWQ(J, 1, 0) DWQ(J, 1, 1) DWQ(J, 1, 2) DWQ(J, 1, 3)
    DWQ(J, 1, 4) DWQ(J, 1, 5) DWQ(J, 1, 6) DWQ(J, 1, 7)
    DWQ(F, 2, 0) DWQ(F, 2, 1) DWQ(F, 2, 2) DWQ(F, 2, 3)
    DWQ(F, 2, 4) DWQ(F, 2, 5) DWQ(F, 2, 6) DWQ(F, 2, 7)
    DWQ(O, 3, 0) DWQ(O, 3, 1) DWQ(O, 3, 2) DWQ(O, 3, 3)
    DWQ(O, 3, 4) DWQ(O, 3, 5) DWQ(O, 3, 6) DWQ(O, 3, 7)
#undef DWQ

    const float w0I = W1[u],        bI = b1[u];
    const float w0J = W1[64 + u],   bJ = b1[64 + u];
    const float w0F = W1[128 + u],  bF = b1[128 + u] + 1.0f;  // forget bias
    const float w0O = W1[192 + u],  bO = b1[192 + u];

    // Layer-2 batch role: lane = tl*4 + g; W2 h-part column g as 32 half2.
    const int tl = lane >> 2, gq = lane & 3;
#define DW2(q) \
    const h2v w2##q##x = pk2(W2[(8*(q)+0)*4 + gq], W2[(8*(q)+1)*4 + gq]); \
    const h2v w2##q##y = pk2(W2[(8*(q)+2)*4 + gq], W2[(8*(q)+3)*4 + gq]); \
    const h2v w2##q##z = pk2(W2[(8*(q)+4)*4 + gq], W2[(8*(q)+5)*4 + gq]); \
    const h2v w2##q##w = pk2(W2[(8*(q)+6)*4 + gq], W2[(8*(q)+7)*4 + gq]);
    DW2(0) DW2(1) DW2(2) DW2(3) DW2(4) DW2(5) DW2(6) DW2(7)
#undef DW2

    float c1 = 0.0f;
    __syncthreads();   // single wave: trivially cheap, covers init stores

    float* __restrict__ zb = zout + (size_t)e * TT * 4;

    // one quad of all 4 gates into accumulator set S (0 for quads 0-3, 1 for 4-7)
#define DGQ(S, q, v) \
    accI##S = DOT2(bch((v).x), wI##q##x, accI##S); \
    accJ##S = DOT2(bch((v).x), wJ##q##x, accJ##S); \
    accF##S = DOT2(bch((v).x), wF##q##x, accF##S); \
    accO##S = DOT2(bch((v).x), wO##q##x, accO##S); \
    accI##S = DOT2(bch((v).y), wI##q##y, accI##S); \
    accJ##S = DOT2(bch((v).y), wJ##q##y, accJ##S); \
    accF##S = DOT2(bch((v).y), wF##q##y, accF##S); \
    accO##S = DOT2(bch((v).y), wO##q##y, accO##S); \
    accI##S = DOT2(bch((v).z), wI##q##z, accI##S); \
    accJ##S = DOT2(bch((v).z), wJ##q##z, accJ##S); \
    accF##S = DOT2(bch((v).z), wF##q##z, accF##S); \
    accO##S = DOT2(bch((v).z), wO##q##z, accO##S); \
    accI##S = DOT2(bch((v).w), wI##q##w, accI##S); \
    accJ##S = DOT2(bch((v).w), wJ##q##w, accJ##S); \
    accF##S = DOT2(bch((v).w), wF##q##w, accF##S); \
    accO##S = DOT2(bch((v).w), wO##q##w, accO##S);

    for (int t = 0; t < TT; ++t) {
        // h(t-1) from ring slot (t-1)&15 (slot 15 zeroed for t=0)
        const int4* hp = (const int4*)&hring[((t - 1) & 15) * 72];
        const int4 q0 = hp[0], q1 = hp[1], q2 = hp[2], q3 = hp[3];
        const int4 q4 = hp[4], q5 = hp[5], q6 = hp[6], q7 = hp[7];
        // two 16-deep chains per gate (dep depth halved vs R19)
        float accI0 = bI, accJ0 = bJ, accF0 = bF, accO0 = bO;
        float accI1 = 0.f, accJ1 = 0.f, accF1 = 0.f, accO1 = 0.f;
        DGQ(0, 0, q0) DGQ(1, 4, q4)
        DGQ(0, 1, q1) DGQ(1, 5, q5)
        DGQ(0, 2, q2) DGQ(1, 6, q6)
        DGQ(0, 3, q3) DGQ(1, 7, q7)
        // x-part folded at the end — x LDS read off the chain front
        const float xt = xall[t];
        const float zI = fmaf(xt, w0I, accI0 + accI1);
        const float zJ = fmaf(xt, w0J, accJ0 + accJ1);
        const float zF = fmaf(xt, w0F, accF0 + accF1);
        const float zO = fmaf(xt, w0O, accO0 + accO1);
        // nonlinearities (all f32)
        const float i_ = fsig(zI);
        const float j_ = ftanh(zJ);
        const float f_ = fsig(zF);            // +1 folded into bF
        const float o_ = fsig(zO);
        c1 = fmaf(c1, f_, i_ * j_);
        const float h1 = ftanh(c1) * o_;
        hring[(t & 15) * 72 + u] = (_Float16)h1;   // same-wave visible (lgkm)

        // layer-2 partial batch every 16 steps (slots 0..15 = steps t-15..t)
        if ((t & 15) == 15) {
            const int4* hb = (const int4*)&hring[tl * 72];
            const int4 b0 = hb[0], b1q = hb[1], b2q = hb[2], b3 = hb[3];
            const int4 b4 = hb[4], b5 = hb[5], b6 = hb[6], b7 = hb[7];
            float z2 = 0.0f;
#define BQ(q, v) \
            z2 = DOT2(bch((v).x), w2##q##x, z2); \
            z2 = DOT2(bch((v).y), w2##q##y, z2); \
            z2 = DOT2(bch((v).z), w2##q##z, z2); \
            z2 = DOT2(bch((v).w), w2##q##w, z2);
            BQ(0, b0) BQ(1, b1q) BQ(2, b2q) BQ(3, b3)
            BQ(4, b4) BQ(5, b5) BQ(6, b6) BQ(7, b7)
#undef BQ
            zb[(size_t)(t - 15 + tl) * 4 + gq] = z2;   // lane-coalesced
        }
    }
#undef DGQ
}

// ===== Kernel 2: layer-2 recurrence (R13, proven, format unchanged) =====
__global__ __launch_bounds__(64)
void lstm2_chain(const float* __restrict__ zp,
                 const float* __restrict__ W2,
                 const float* __restrict__ b2,
                 float* __restrict__ out)
{
    const int lane = threadIdx.x & 63;
    const int e    = lane >> 2;
    const int g    = lane & 3;
    const int elem = (blockIdx.x << 4) + e;

    const float w2h = W2[256 + g];
    const float bb  = b2[g] + ((g == 2) ? 1.0f : 0.0f);
    const float nlm = (g == 1) ? -2.0f : -1.0f;
    const float k2  = (g == 1) ?  2.0f :  1.0f;
    const float k3  = (g == 1) ? -1.0f :  0.0f;

    const float* __restrict__ zrow = zp + (size_t)elem * TT * 4 + g;
    float* __restrict__ orow = out + (size_t)elem * TT;

    float c2 = 0.0f, h2 = 0.0f;

    float zc[16];
#pragma unroll
    for (int k = 0; k < 16; ++k) zc[k] = zrow[k << 2];

    for (int t0 = 0; t0 < TT; t0 += 16) {
        float zn[16];
        if (t0 + 16 < TT) {
#pragma unroll
            for (int k = 0; k < 16; ++k) zn[k] = zrow[((t0 + 16 + k) << 2)];
        }
        float st0 = 0.f, st1 = 0.f, st2 = 0.f, st3 = 0.f;
#pragma unroll
        for (int k = 0; k < 16; ++k) {
            const float arg = fmaf(w2h, h2, zc[k] + bb);
            const float ev  = __expf(arg * nlm);
            const float rv  = rcpf(1.0f + ev);
            const float v   = fmaf(k2, rv, k3);
            const float vi = qbcast<0>(v), vj = qbcast<1>(v);
            const float vf = qbcast<2>(v), vo = qbcast<3>(v);
            c2 = fmaf(c2, vf, vi * vj);
            h2 = ftanh(c2) * vo;
            const bool mine = (g == (k & 3));
            if ((k >> 2) == 0) st0 = mine ? h2 : st0;
            else if ((k >> 2) == 1) st1 = mine ? h2 : st1;
            else if ((k >> 2) == 2) st2 = mine ? h2 : st2;
            else st3 = mine ? h2 : st3;
        }
        orow[t0 + g]      = st0;
        orow[t0 + 4 + g]  = st1;
        orow[t0 + 8 + g]  = st2;
        orow[t0 + 12 + g] = st3;
#pragma unroll
        for (int k = 0; k < 16; ++k) zc[k] = zn[k];
    }
}

// ===== Fallback: monolithic (R11 core, proven) =====
__global__ __launch_bounds__(512)
__attribute__((amdgpu_waves_per_eu(4, 4)))
void lstm2_mono(const float* __restrict__ x,
                const float* __restrict__ W1,
                const float* __restrict__ b1,
                const float* __restrict__ W2,
                const float* __restrict__ b2,
                float* __restrict__ out)
{
    __shared__ __align__(16) float xall[TT + 4];
    __shared__ __align__(16) float h1x[2][80];
    __shared__ __align__(16) float zpq[4][4];
    __shared__ __align__(16) float h2buf[2][64];

    const int tid  = threadIdx.x;
    const int wave = tid >> 6;
    const int lane = tid & 63;
    const int b    = blockIdx.x;

    for (int i = tid; i < TT; i += 512) xall[i] = x[b * TT + i];
    if (tid < 4) xall[TT + tid] = 0.0f;

    const int u    = lane >> 3;
    const int h    = (lane >> 2) & 1;
    const int g    = lane & 3;
    const int unit = (wave << 3) + u;
    const int col  = (g << 6) + unit;

#define DECLW(k) const v2f wq##k = mk2(W1[(1 + 32*h + 2*(k)) * 256 + col], \
                                       W1[(2 + 32*h + 2*(k)) * 256 + col]);
    DECLW(0)  DECLW(1)  DECLW(2)  DECLW(3)
    DECLW(4)  DECLW(5)  DECLW(6)  DECLW(7)
    DECLW(8)  DECLW(9)  DECLW(10) DECLW(11)
    DECLW(12) DECLW(13) DECLW(14) DECLW(15)
#undef DECLW

    const float w0x   = (h == 0) ? W1[col] : 0.0f;
    const float biasF = (h == 0) ? (b1[col] + ((g == 2) ? 1.0f : 0.0f)) : 0.0f;
    const float nlm   = (g == 1) ? -2.0f : -1.0f;
    const bool  isj   = (g == 1);

    const float w2g  = W2[lane * 4 + (wave & 3)];
    const float w2h0 = W2[256], w2h1 = W2[257], w2h2 = W2[258], w2h3 = W2[259];
    const float b20 = b2[0], b21 = b2[1], b22 = b2[2], b23 = b2[3];

    float c1 = 0.0f;
    float c2 = 0.0f, h2v2 = 0.0f;

    const int hbase = h * 48;
    const int ridx  = lane + ((lane >> 5) << 4);
    const int widx  = (unit < 32) ? unit : unit + 16;

    if (tid < 160) ((float*)h1x)[tid] = 0.0f;
    __syncthreads();

    float* __restrict__ outb = out + b * TT;

#define WSUM(s) ({ float _s = (s);                                            \
    _s += dppmov<0x111>(_s); _s += dppmov<0x112>(_s); _s += dppmov<0x114>(_s);\
    _s += dppmov<0x118>(_s); _s += dppmov<0x142>(_s); _s += dppmov<0x143>(_s);\
    _s; })

#define STEP(P, t, xv)                                                        \
    {                                                                         \
        if ((t) < TT) {                                                       \
            const float4* hp = (const float4*)&h1x[P][hbase];                 \
            const float4 q0 = hp[0], q1 = hp[1], q2 = hp[2], q3 = hp[3];      \
            const float4 q4 = hp[4], q5 = hp[5], q6 = hp[6], q7 = hp[7];      \
            v2f a0 = mk2(fmaf((xv), w0x, biasF), 0.0f);                       \
            v2f a1 = mk2(0.f, 0.f), a2 = mk2(0.f, 0.f), a3 = mk2(0.f, 0.f);  \
            a0 = __builtin_elementwise_fma(mk2(q0.x, q0.y), wq0,  a0);        \
            a1 = __builtin_elementwise_fma(mk2(q0.z, q0.w), wq1,  a1);        \
            a2 = __builtin_elementwise_fma(mk2(q1.x, q1.y), wq2,  a2);        \
            a3 = __builtin_elementwise_fma(mk2(q1.z, q1.w), wq3,  a3);        \
            a0 = __builtin_elementwise_fma(mk2(q2.x, q2.y), wq4,  a0);        \
            a1 = __builtin_elementwise_fma(mk2(q2.z, q2.w), wq5,  a1);        \
            a2 = __builtin_elementwise_fma(mk2(q3.x, q3.y), wq6,  a2);        \
            a3 = __builtin_elementwise_fma(mk2(q3.z, q3.w), wq7,  a3);        \
            a0 = __builtin_elementwise_fma(mk2(q4.x, q4.y), wq8,  a0);        \
            a1 = __builtin_elementwise_fma(mk2(q4.z, q4.w), wq9,  a1);        \
            a2 = __builtin_elementwise_fma(mk2(q5.x, q5.y), wq10, a2);        \
            a3 = __builtin_elementwise_fma(mk2(q5.z, q5.w), wq11, a3);        \
            a0 = __builtin_elementwise_fma(mk2(q6.x, q6.y), wq12, a0);        \
            a1 = __builtin_elementwise_fma(mk2(q6.z, q6.w), wq13, a1);        \
            a2 = __builtin_elementwise_fma(mk2(q7.x, q7.y), wq14, a2);        \
            a3 = __builtin_elementwise_fma(mk2(q7.z, q7.w), wq15, a3);        \
            const v2f sv = (a0 + a1) + (a2 + a3);                             \
            const float zh = sv.x + sv.y;                                     \
            const float tshr = dppmov<0x114>(zh);                             \
            const float tshl = dppmov<0x104>(zh);                             \
            const float zfull = zh + (h ? tshr : tshl);                       \
            const float e = __expf(zfull * nlm);                              \
            const float r = rcpf(1.0f + e);                                   \
            const float v = isj ? fmaf(2.0f, r, -1.0f) : r;                   \
            const float gi = qbcast<0>(v), gj = qbcast<1>(v);                 \
            const float gf = qbcast<2>(v), go = qbcast<3>(v);                 \
            c1 = fmaf(c1, gf, gi * gj);                                       \
            const float h1v = ftanh(c1) * go;                                 \
            if ((lane & 7) == 0) h1x[(P) ^ 1][widx] = h1v;                    \
        }                                                                     \
        if (wave < 4 && (t) >= 1 && (t) <= TT) {                              \
            const float s = WSUM(h1x[P][ridx] * w2g);                         \
            if (lane == 63) zpq[((t) - 1) & 3][wave] = s;                     \
        }                                                                     \
        if (wave == 7 && lane == 0 && (t) >= 2 && (t) <= TT + 1) {            \
            const int st = (t) - 2;                                           \
            const float4 z4 = *(const float4*)zpq[st & 3];                    \
            const float zi = z4.x + fmaf(h2v2, w2h0, b20);                    \
            const float zj = z4.y + fmaf(h2v2, w2h1, b21);                    \
            const float zf = z4.z + fmaf(h2v2, w2h2, b22);                    \
            const float zo = z4.w + fmaf(h2v2, w2h3, b23);                    \
            c2 = c2 * fsig(zf + 1.0f) + fsig(zi) * ftanh(zj);                 \
            h2v2 = ftanh(c2) * fsig(zo);                                      \
            h2buf[(st >> 6) & 1][st & 63] = h2v2;                             \
        }                                                                     \
        __syncthreads();                                                      \
        if (wave == 4 && (t) >= 66 && ((t) & 63) == 2) {                      \
            const int blk = ((t) - 66) >> 6;                                  \
            outb[(blk << 6) + lane] = h2buf[blk & 1][lane];                   \
        }                                                                     \
    }

    for (int it = 0; it <= TT + 2; it += 2) {
        const float2 x2 = *(const float2*)&xall[it];
        STEP(0, it,     x2.x)
        STEP(1, it + 1, x2.y)
    }
#undef STEP
#undef WSUM
}

extern "C" void kernel_launch(void* const* d_in, const int* in_sizes, int n_in,
                              void* d_out, int out_size, void* d_ws, size_t ws_size,
                              hipStream_t stream)
{
    const float* x  = (const float*)d_in[0];
    const float* W1 = (const float*)d_in[1];
    const float* b1 = (const float*)d_in[2];
    const float* W2 = (const float*)d_in[3];
    const float* b2 = (const float*)d_in[4];
    float* out = (float*)d_out;

    const size_t need = (size_t)512 * TT * 4 * sizeof(float);   // 16.8 MB
    if (ws_size >= need) {
        float* zp = (float*)d_ws;
        lstm1_f16<<<512, 64, 0, stream>>>(x, W1, b1, W2, zp);
        lstm2_chain<<<512 / 16, 64, 0, stream>>>(zp, W2, b2, out);
    } else {
        lstm2_mono<<<512, 512, 0, stream>>>(x, W1, b1, W2, b2, out);
    }
}

// Round 23
// 1038.881 us; speedup vs baseline: 1.6108x; 1.0005x over previous
//
#include <hip/hip_runtime.h>

#define TT 2048

typedef float v2f __attribute__((ext_vector_type(2)));
typedef _Float16 h2v __attribute__((ext_vector_type(2)));

__device__ __forceinline__ v2f mk2(float a, float b) { v2f r; r.x = a; r.y = b; return r; }
__device__ __forceinline__ float rcpf(float x) { return __builtin_amdgcn_rcpf(x); }
__device__ __forceinline__ float fsig(float x) { return rcpf(1.0f + __expf(-x)); }
__device__ __forceinline__ float ftanh(float x) {
    return fmaf(2.0f, rcpf(1.0f + __expf(-2.0f * x)), -1.0f);
}

template<int C>
__device__ __forceinline__ float dppmov(float s) {
    return __int_as_float(__builtin_amdgcn_update_dpp(
        __float_as_int(s), __float_as_int(s), C, 0xF, 0xF, false));
}
template<int Q>
__device__ __forceinline__ float qbcast(float x) {
    return __int_as_float(__builtin_amdgcn_update_dpp(
        __float_as_int(x), __float_as_int(x), Q * 0x55, 0xF, 0xF, false));
}

#if __has_builtin(__builtin_amdgcn_fdot2)
#define DOT2(a, b, c) __builtin_amdgcn_fdot2((a), (b), (c), false)
#else
#define DOT2(a, b, c) fmaf((float)(a).x, (float)(b).x, \
                      fmaf((float)(a).y, (float)(b).y, (c)))
#endif

__device__ __forceinline__ h2v pk2(float a, float b) {
#if __has_builtin(__builtin_amdgcn_cvt_pkrtz)
    return __builtin_bit_cast(h2v, __builtin_amdgcn_cvt_pkrtz(a, b));
#else
    h2v r; r.x = (_Float16)a; r.y = (_Float16)b; return r;
#endif
}
__device__ __forceinline__ h2v bch(int v) { return __builtin_bit_cast(h2v, v); }

// ===== Kernel 1: ONE WAVE PER ELEMENT, register demand fit to the ~128 cap ==
// R19-R22 post-mortem: allocator hard-caps this shape at ~124-132 VGPR
// (ignores waves_per_eu and amdgpu_num_vgpr), so R19/R22's 160-reg demand
// meant ~36 h2v of weights re-fetched from L2 (~200cyc) EVERY step. Fix:
// fit the cap. I,J gate weights stay in registers (64 h2v — the size the
// allocator demonstrably grants, R16: 88 VGPR). F,O gate weights live in
// LDS as h2v pairs [gate][kpair][u] (lane u reads word u of a row:
// consecutive words, 2-way alias = free, m136) -> 32 ds_read_b32/step
// whose latency hides under the ring round trip + I/J register dots.
// W2 in LDS (R21-proven neutral). Demand ~110-125 <= cap -> no L2 reloads.
__global__ __launch_bounds__(64)
__attribute__((amdgpu_waves_per_eu(2, 2)))
void lstm1_f16(const float* __restrict__ x,
               const float* __restrict__ W1,
               const float* __restrict__ b1,
               const float* __restrict__ W2,
               float* __restrict__ zout)
{
    __shared__ __align__(16) float xall[TT];
    __shared__ __align__(16) _Float16 hring[16 * 72];  // 144B/slot
    __shared__ __align__(16) int wFOi[2][32][64];      // F,O weights (h2v pairs)
    __shared__ __align__(16) _Float16 w2lds[4][72];    // W2 rows (batch phase)

    const int lane = threadIdx.x & 63;
    const int e    = blockIdx.x;
    const int u    = lane;

    for (int i = lane; i < TT; i += 64) xall[i] = x[(size_t)e * TT + i];
    for (int i = lane; i < 576; i += 64) ((int*)hring)[i] = 0;
    // F (gate 2) and O (gate 3) weights into LDS as packed pairs
    for (int kp = 0; kp < 32; ++kp) {
        wFOi[0][kp][u] = __builtin_bit_cast(int,
            pk2(W1[(1 + 2*kp)*256 + 128 + u], W1[(2 + 2*kp)*256 + 128 + u]));
        wFOi[1][kp][u] = __builtin_bit_cast(int,
            pk2(W1[(1 + 2*kp)*256 + 192 + u], W1[(2 + 2*kp)*256 + 192 + u]));
    }
    w2lds[0][lane] = (_Float16)W2[lane * 4 + 0];
    w2lds[1][lane] = (_Float16)W2[lane * 4 + 1];
    w2lds[2][lane] = (_Float16)W2[lane * 4 + 2];
    w2lds[3][lane] = (_Float16)W2[lane * 4 + 3];

    // I (gate 0), J (gate 1) weights in registers: 32 h2v each.
#define DWQ(G, GO, q) \
    const h2v w##G##q##x = pk2(W1[(1+8*(q))*256 + (GO)*64 + u], W1[(2+8*(q))*256 + (GO)*64 + u]); \
    const h2v w##G##q##y = pk2(W1[(3+8*(q))*256 + (GO)*64 + u], W1[(4+8*(q))*256 + (GO)*64 + u]); \
    const h2v w##G##q##z = pk2(W1[(5+8*(q))*256 + (GO)*64 + u], W1[(6+8*(q))*256 + (GO)*64 + u]); \
    const h2v w##G##q##w = pk2(W1[(7+8*(q))*256 + (GO)*64 + u], W1[(8+8*(q))*256 + (GO)*64 + u]);
    DWQ(I, 0, 0) DWQ(I, 0, 1) DWQ(I, 0, 2) DWQ(I, 0, 3)
    DWQ(I, 0, 4) DWQ(I, 0, 5) DWQ(I, 0, 6) DWQ(I, 0, 7)
    DWQ(J, 1, 0) DWQ(J, 1, 1) DWQ(J, 1, 2) DWQ(J, 1, 3)
    DWQ(J, 1, 4) DWQ(J, 1, 5) DWQ(J, 1, 6) DWQ(J, 1, 7)
#undef DWQ

    const float w0I = W1[u],        bI = b1[u];
    const float w0J = W1[64 + u],   bJ = b1[64 + u];
    const float w0F = W1[128 + u],  bF = b1[128 + u] + 1.0f;  // forget bias
    const float w0O = W1[192 + u],  bO = b1[192 + u];

    const int tl = lane >> 2, gq = lane & 3;   // layer-2 batch role

    float c1 = 0.0f;
    __syncthreads();   // single wave: covers init stores

    float* __restrict__ zb = zout + (size_t)e * TT * 4;
    const int* __restrict__ wFp = &wFOi[0][0][0] + u;   // + kp*64
    const int* __restrict__ wOp = &wFOi[1][0][0] + u;

    // I,J dots from register weights, accumulator set S
#define DGIJ(S, q, v) \
    accI##S = DOT2(bch((v).x), wI##q##x, accI##S); \
    accJ##S = DOT2(bch((v).x), wJ##q##x, accJ##S); \
    accI##S = DOT2(bch((v).y), wI##q##y, accI##S); \
    accJ##S = DOT2(bch((v).y), wJ##q##y, accJ##S); \
    accI##S = DOT2(bch((v).z), wI##q##z, accI##S); \
    accJ##S = DOT2(bch((v).z), wJ##q##z, accJ##S); \
    accI##S = DOT2(bch((v).w), wI##q##w, accI##S); \
    accJ##S = DOT2(bch((v).w), wJ##q##w, accJ##S);
    // F,O dots from LDS weights (kp-th pair row), accumulator set S
#define FOD(S, kp, comp) \
    accF##S = DOT2(bch(comp), bch(wFp[(kp) * 64]), accF##S); \
    accO##S = DOT2(bch(comp), bch(wOp[(kp) * 64]), accO##S);

    for (int t = 0; t < TT; ++t) {
        // h(t-1) ring reads issue first (latency spans the FO weight reads)
        const int4* hp = (const int4*)&hring[((t - 1) & 15) * 72];
        const int4 q0 = hp[0], q1 = hp[1], q2 = hp[2], q3 = hp[3];
        const int4 q4 = hp[4], q5 = hp[5], q6 = hp[6], q7 = hp[7];
        float accI0 = bI, accJ0 = bJ, accF0 = bF, accO0 = bO;
        float accI1 = 0.f, accJ1 = 0.f, accF1 = 0.f, accO1 = 0.f;
        // register-weight dots (only ring-dependent) — run while FO reads land
        DGIJ(0, 0, q0) DGIJ(1, 4, q4)
        DGIJ(0, 1, q1) DGIJ(1, 5, q5)
        DGIJ(0, 2, q2) DGIJ(1, 6, q6)
        DGIJ(0, 3, q3) DGIJ(1, 7, q7)
        // LDS-weight dots: kp 0..15 -> chain0 (q0..q3), 16..31 -> chain1
        FOD(0, 0,  q0.x) FOD(1, 16, q4.x)
        FOD(0, 1,  q0.y) FOD(1, 17, q4.y)
        FOD(0, 2,  q0.z) FOD(1, 18, q4.z)
        FOD(0, 3,  q0.w) FOD(1, 19, q4.w)
        FOD(0, 4,  q1.x) FOD(1, 20, q5.x)
        FOD(0, 5,  q1.y) FOD(1, 21, q5.y)
        FOD(0, 6,  q1.z) FOD(1, 22, q5.z)
        FOD(0, 7,  q1.w) FOD(1, 23, q5.w)
        FOD(0, 8,  q2.x) FOD(1, 24, q6.x)
        FOD(0, 9,  q2.y) FOD(1, 25, q6.y)
        FOD(0, 10, q2.z) FOD(1, 26, q6.z)
        FOD(0, 11, q2.w) FOD(1, 27, q6.w)
        FOD(0, 12, q3.x) FOD(1, 28, q7.x)
        FOD(0, 13, q3.y) FOD(1, 29, q7.y)
        FOD(0, 14, q3.z) FOD(1, 30, q7.z)
        FOD(0, 15, q3.w) FOD(1, 31, q7.w)
        // x-part folded at the end
        const float xt = xall[t];
        const float zI = fmaf(xt, w0I, accI0 + accI1);
        const float zJ = fmaf(xt, w0J, accJ0 + accJ1);
        const float zF = fmaf(xt, w0F, accF0 + accF1);
        const float zO = fmaf(xt, w0O, accO0 + accO1);
        // nonlinearities (all f32)
        const float i_ = fsig(zI);
        const float j_ = ftanh(zJ);
        const float f_ = fsig(zF);            // +1 folded into bF
        const float o_ = fsig(zO);
        c1 = fmaf(c1, f_, i_ * j_);
        const float h1 = ftanh(c1) * o_;
        hring[(t & 15) * 72 + u] = (_Float16)h1;   // same-wave visible (lgkm)

        // layer-2 partial batch every 16 steps (W2 from LDS)
        if ((t & 15) == 15) {
            const int4* hb  = (const int4*)&hring[tl * 72];
            const int4* w2q = (const int4*)&w2lds[gq][0];
            float z2 = 0.0f;
#pragma unroll
            for (int q = 0; q < 8; ++q) {
                const int4 wv = w2q[q];
                const int4 va = hb[q];
                z2 = DOT2(bch(va.x), bch(wv.x), z2);
                z2 = DOT2(bch(va.y), bch(wv.y), z2);
                z2 = DOT2(bch(va.z), bch(wv.z), z2);
                z2 = DOT2(bch(va.w), bch(wv.w), z2);
            }
            zb[(size_t)(t - 15 + tl) * 4 + gq] = z2;   // lane-coalesced
        }
    }
#undef DGIJ
#undef FOD
}

// ===== Kernel 2: layer-2 recurrence (R13, proven, format unchanged) =====
__global__ __launch_bounds__(64)
void lstm2_chain(const float* __restrict__ zp,
                 const float* __restrict__ W2,
                 const float* __restrict__ b2,
                 float* __restrict__ out)
{
    const int lane = threadIdx.x & 63;
    const int e    = lane >> 2;
    const int g    = lane & 3;
    const int elem = (blockIdx.x << 4) + e;

    const float w2h = W2[256 + g];
    const float bb  = b2[g] + ((g == 2) ? 1.0f : 0.0f);
    const float nlm = (g == 1) ? -2.0f : -1.0f;
    const float k2  = (g == 1) ?  2.0f :  1.0f;
    const float k3  = (g == 1) ? -1.0f :  0.0f;

    const float* __restrict__ zrow = zp + (size_t)elem * TT * 4 + g;
    float* __restrict__ orow = out + (size_t)elem * TT;

    float c2 = 0.0f, h2 = 0.0f;

    float zc[16];
#pragma unroll
    for (int k = 0; k < 16; ++k) zc[k] = zrow[k << 2];

    for (int t0 = 0; t0 < TT; t0 += 16) {
        float zn[16];
        if (t0 + 16 < TT) {
#pragma unroll
            for (int k = 0; k < 16; ++k) zn[k] = zrow[((t0 + 16 + k) << 2)];
        }
        float st0 = 0.f, st1 = 0.f, st2 = 0.f, st3 = 0.f;
#pragma unroll
        for (int k = 0; k < 16; ++k) {
            const float arg = fmaf(w2h, h2, zc[k] + bb);
            const float ev  = __expf(arg * nlm);
            const float rv  = rcpf(1.0f + ev);
            const float v   = fmaf(k2, rv, k3);
            const float vi = qbcast<0>(v), vj = qbcast<1>(v);
            const float vf = qbcast<2>(v), vo = qbcast<3>(v);
            c2 = fmaf(c2, vf, vi * vj);
            h2 = ftanh(c2) * vo;
            const bool mine = (g == (k & 3));
            if ((k >> 2) == 0) st0 = mine ? h2 : st0;
            else if ((k >> 2) == 1) st1 = mine ? h2 : st1;
            else if ((k >> 2) == 2) st2 = mine ? h2 : st2;
            else st3 = mine ? h2 : st3;
        }
        orow[t0 + g]      = st0;
        orow[t0 + 4 + g]  = st1;
        orow[t0 + 8 + g]  = st2;
        orow[t0 + 12 + g] = st3;
#pragma unroll
        for (int k = 0; k < 16; ++k) zc[k] = zn[k];
    }
}

// ===== Fallback: monolithic (R11 core, proven) =====
__global__ __launch_bounds__(512)
__attribute__((amdgpu_waves_per_eu(4, 4)))
void lstm2_mono(const float* __restrict__ x,
                const float* __restrict__ W1,
                const float* __restrict__ b1,
                const float* __restrict__ W2,
                const float* __restrict__ b2,
                float* __restrict__ out)
{
    __shared__ __align__(16) float xall[TT + 4];
    __shared__ __align__(16) float h1x[2][80];
    __shared__ __align__(16) float zpq[4][4];
    __shared__ __align__(16) float h2buf[2][64];

    const int tid  = threadIdx.x;
    const int wave = tid >> 6;
    const int lane = tid & 63;
    const int b    = blockIdx.x;

    for (int i = tid; i < TT; i += 512) xall[i] = x[b * TT + i];
    if (tid < 4) xall[TT + tid] = 0.0f;

    const int u    = lane >> 3;
    const int h    = (lane >> 2) & 1;
    const int g    = lane & 3;
    const int unit = (wave << 3) + u;
    const int col  = (g << 6) + unit;

#define DECLW(k) const v2f wq##k = mk2(W1[(1 + 32*h + 2*(k)) * 256 + col], \
                                       W1[(2 + 32*h + 2*(k)) * 256 + col]);
    DECLW(0)  DECLW(1)  DECLW(2)  DECLW(3)
    DECLW(4)  DECLW(5)  DECLW(6)  DECLW(7)
    DECLW(8)  DECLW(9)  DECLW(10) DECLW(11)
    DECLW(12) DECLW(13) DECLW(14) DECLW(15)
#undef DECLW

    const float w0x   = (h == 0) ? W1[col] : 0.0f;
    const float biasF = (h == 0) ? (b1[col] + ((g == 2) ? 1.0f : 0.0f)) : 0.0f;
    const float nlm   = (g == 1) ? -2.0f : -1.0f;
    const bool  isj   = (g == 1);

    const float w2g  = W2[lane * 4 + (wave & 3)];
    const float w2h0 = W2[256], w2h1 = W2[257], w2h2 = W2[258], w2h3 = W2[259];
    const float b20 = b2[0], b21 = b2[1], b22 = b2[2], b23 = b2[3];

    float c1 = 0.0f;
    float c2 = 0.0f, h2v2 = 0.0f;

    const int hbase = h * 48;
    const int ridx  = lane + ((lane >> 5) << 4);
    const int widx  = (unit < 32) ? unit : unit + 16;

    if (tid < 160) ((float*)h1x)[tid] = 0.0f;
    __syncthreads();

    float* __restrict__ outb = out + b * TT;

#define WSUM(s) ({ float _s = (s);                                            \
    _s += dppmov<0x111>(_s); _s += dppmov<0x112>(_s); _s += dppmov<0x114>(_s);\
    _s += dppmov<0x118>(_s); _s += dppmov<0x142>(_s); _s += dppmov<0x143>(_s);\
    _s; })

#define STEP(P, t, xv)                                                        \
    {                                                                         \
        if ((t) < TT) {                                                       \
            const float4* hp = (const float4*)&h1x[P][hbase];                 \
            const float4 q0 = hp[0], q1 = hp[1], q2 = hp[2], q3 = hp[3];      \
            const float4 q4 = hp[4], q5 = hp[5], q6 = hp[6], q7 = hp[7];      \
            v2f a0 = mk2(fmaf((xv), w0x, biasF), 0.0f);                       \
            v2f a1 = mk2(0.f, 0.f), a2 = mk2(0.f, 0.f), a3 = mk2(0.f, 0.f);  \
            a0 = __builtin_elementwise_fma(mk2(q0.x, q0.y), wq0,  a0);        \
            a1 = __builtin_elementwise_fma(mk2(q0.z, q0.w), wq1,  a1);        \
            a2 = __builtin_elementwise_fma(mk2(q1.x, q1.y), wq2,  a2);        \
            a3 = __builtin_elementwise_fma(mk2(q1.z, q1.w), wq3,  a3);        \
            a0 = __builtin_elementwise_fma(mk2(q2.x, q2.y), wq4,  a0);        \
            a1 = __builtin_elementwise_fma(mk2(q2.z, q2.w), wq5,  a1);        \
            a2 = __builtin_elementwise_fma(mk2(q3.x, q3.y), wq6,  a2);        \
            a3 = __builtin_elementwise_fma(mk2(q3.z, q3.w), wq7,  a3);        \
            a0 = __builtin_elementwise_fma(mk2(q4.x, q4.y), wq8,  a0);        \
            a1 = __builtin_elementwise_fma(mk2(q4.z, q4.w), wq9,  a1);        \
            a2 = __builtin_elementwise_fma(mk2(q5.x, q5.y), wq10, a2);        \
            a3 = __builtin_elementwise_fma(mk2(q5.z, q5.w), wq11, a3);        \
            a0 = __builtin_elementwise_fma(mk2(q6.x, q6.y), wq12, a0);        \
            a1 = __builtin_elementwise_fma(mk2(q6.z, q6.w), wq13, a1);        \
            a2 = __builtin_elementwise_fma(mk2(q7.x, q7.y), wq14, a2);        \
            a3 = __builtin_elementwise_fma(mk2(q7.z, q7.w), wq15, a3);        \
            const v2f sv = (a0 + a1) + (a2 + a3);                             \
            const float zh = sv.x + sv.y;                                     \
            const float tshr = dppmov<0x114>(zh);                             \
            const float tshl = dppmov<0x104>(zh);                             \
            const float zfull = zh + (h ? tshr : tshl);                       \
            const float e = __expf(zfull * nlm);                              \
            const float r = rcpf(1.0f + e);                                   \
            const float v = isj ? fmaf(2.0f, r, -1.0f) : r;                   \
            const float gi = qbcast<0>(v), gj = qbcast<1>(v);                 \
            const float gf = qbcast<2>(v), go = qbcast<3>(v);                 \
            c1 = fmaf(c1, gf, gi * gj);                                       \
            const float h1v = ftanh(c1) * go;                                 \
            if ((lane & 7) == 0) h1x[(P) ^ 1][widx] = h1v;                    \
        }                                                                     \
        if (wave < 4 && (t) >= 1 && (t) <= TT) {                              \
            const float s = WSUM(h1x[P][ridx] * w2g);                         \
            if (lane == 63) zpq[((t) - 1) & 3][wave] = s;                     \
        }                                                                     \
        if (wave == 7 && lane == 0 && (t) >= 2 && (t) <= TT + 1) {            \
            const int st = (t) - 2;                                           \
            const float4 z4 = *(const float4*)zpq[st & 3];                    \
            const float zi = z4.x + fmaf(h2v2, w2h0, b20);                    \
            const float zj = z4.y + fmaf(h2v2, w2h1, b21);                    \
            const float zf = z4.z + fmaf(h2v2, w2h2, b22);                    \
            const float zo = z4.w + fmaf(h2v2, w2h3, b23);                    \
            c2 = c2 * fsig(zf + 1.0f) + fsig(zi) * ftanh(zj);                 \
            h2v2 = ftanh(c2) * fsig(zo);                                      \
            h2buf[(st >> 6) & 1][st & 63] = h2v2;                             \
        }                                                                     \
        __syncthreads();                                                      \
        if (wave == 4 && (t) >= 66 && ((t) & 63) == 2) {                      \
            const int blk = ((t) - 66) >> 6;                                  \
            outb[(blk << 6) + lane] = h2buf[blk & 1][lane];                   \
        }                                                                     \
    }

    for (int it = 0; it <= TT + 2; it += 2) {
        const float2 x2 = *(const float2*)&xall[it];
        STEP(0, it,     x2.x)
        STEP(1, it + 1, x2.y)
    }
#undef STEP
#undef WSUM
}

extern "C" void kernel_launch(void* const* d_in, const int* in_sizes, int n_in,
                              void* d_out, int out_size, void* d_ws, size_t ws_size,
                              hipStream_t stream)
{
    const float* x  = (const float*)d_in[0];
    const float* W1 = (const float*)d_in[1];
    const float* b1 = (const float*)d_in[2];
    const float* W2 = (const float*)d_in[3];
    const float* b2 = (const float*)d_in[4];
    float* out = (float*)d_out;

    const size_t need = (size_t)512 * TT * 4 * sizeof(float);   // 16.8 MB
    if (ws_size >= need) {
        float* zp = (float*)d_ws;
        lstm1_f16<<<512, 64, 0, stream>>>(x, W1, b1, W2, zp);
        lstm2_chain<<<512 / 16, 64, 0, stream>>>(zp, W2, b2, out);
    } else {
        lstm2_mono<<<512, 512, 0, stream>>>(x, W1, b1, W2, b2, out);
    }
}